// Round 1
// baseline (624.647 us; speedup 1.0000x reference)
//
#include <hip/hip_runtime.h>
#include <cstdint>
#include <cstddef>

// Problem constants: x (B=8, C=64, H=32, W=32, D=32) fp32; codebook (512, 64) fp32.
#define SPATIAL   32768          // H*W*D
#define CHANNELS  64
#define NUM_EMB   512
#define NPOS      262144         // B * SPATIAL
#define OUT_ELEMS 16777216       // NPOS * CHANNELS
// loss = q_loss + 0.25*e_loss = 1.25 * mean((quant-x)^2); 1.25/2^24 = 5*2^-26 exact in fp32
#define LOSS_SCALE (1.25f / 16777216.0f)

// numpy pairwise_sum for n=64 (contiguous): 8 accumulators strided by 8,
// combined ((r0+r1)+(r2+r3))+((r4+r5)+(r6+r7)). Bitwise replication.
__device__ __forceinline__ float np_pairwise_sum64(const float* v) {
#pragma clang fp contract(off)
    float r[8];
#pragma unroll
    for (int j = 0; j < 8; ++j) r[j] = v[j];
#pragma unroll
    for (int i = 8; i < 64; i += 8) {
#pragma unroll
        for (int j = 0; j < 8; ++j) r[j] += v[i + j];
    }
    return ((r[0] + r[1]) + (r[2] + r[3])) + ((r[4] + r[5]) + (r[6] + r[7]));
}

// Prep: cb2 = 2*codebook (exact), cbnorm[e] = numpy-pairwise sum(cb[e]^2), zero loss slot.
__global__ void vq_prep(const float* __restrict__ cb,
                        float* __restrict__ cb2,
                        float* __restrict__ cbnorm,
                        float* __restrict__ loss_slot) {
#pragma clang fp contract(off)
    int e = blockIdx.x * blockDim.x + threadIdx.x;
    if (e == 0) *loss_slot = 0.0f;
    if (e < NUM_EMB) {
        float sq[CHANNELS];
#pragma unroll
        for (int c = 0; c < CHANNELS; ++c) {
            float v = cb[e * CHANNELS + c];
            cb2[e * CHANNELS + c] = v + v;   // exact
            sq[c] = v * v;                   // numpy: cb*cb rounded, then summed
        }
        cbnorm[e] = np_pairwise_sum64(sq);
    }
}

__global__ __launch_bounds__(256) void vq_main(
    const float* __restrict__ x,
    const float* __restrict__ cb,
    const float* __restrict__ cb2,
    const float* __restrict__ cbnorm,
    float* __restrict__ out,
    float* __restrict__ loss_slot) {
#pragma clang fp contract(off)
    const int n = blockIdx.x * 256 + threadIdx.x;   // position index, < NPOS
    const int b = n >> 15;                          // / SPATIAL
    const int s = n & 32767;                        // % SPATIAL

    const float* xp = x + (size_t)b * (CHANNELS * SPATIAL) + s;

    // Load the 64-channel vector (stride SPATIAL -> coalesced across lanes per c)
    float xv[CHANNELS];
#pragma unroll
    for (int c = 0; c < CHANNELS; ++c) xv[c] = xp[(size_t)c * SPATIAL];

    // ||x||^2, numpy pairwise on elementwise squares
    float sq[CHANNELS];
#pragma unroll
    for (int c = 0; c < CHANNELS; ++c) sq[c] = xv[c] * xv[c];
    const float a = np_pairwise_sum64(sq);

    // Argmin over 512 entries. Score s_e = (a - (2x)·cb_e) + ||cb_e||^2,
    // dot replicated as sequential k-ascending fma chain (BLAS sgemm order):
    // fma(x_c, 2*cb_c, acc) == fma(2*x_c, cb_c, acc) bitwise (product identical).
    const float4* cb4 = (const float4*)cb2;         // 16 float4 per row
    float best = 3.4e38f;
    int bidx = 0;

    for (int e0 = 0; e0 < NUM_EMB; e0 += 4) {
        float a0 = 0.0f, a1 = 0.0f, a2 = 0.0f, a3 = 0.0f;
        const float4* r = cb4 + (size_t)e0 * 16;
#pragma unroll
        for (int c4 = 0; c4 < 16; ++c4) {
            float4 v0 = r[c4];
            float4 v1 = r[16 + c4];
            float4 v2 = r[32 + c4];
            float4 v3 = r[48 + c4];
            a0 = __builtin_fmaf(xv[4 * c4 + 0], v0.x, a0);
            a0 = __builtin_fmaf(xv[4 * c4 + 1], v0.y, a0);
            a0 = __builtin_fmaf(xv[4 * c4 + 2], v0.z, a0);
            a0 = __builtin_fmaf(xv[4 * c4 + 3], v0.w, a0);
            a1 = __builtin_fmaf(xv[4 * c4 + 0], v1.x, a1);
            a1 = __builtin_fmaf(xv[4 * c4 + 1], v1.y, a1);
            a1 = __builtin_fmaf(xv[4 * c4 + 2], v1.z, a1);
            a1 = __builtin_fmaf(xv[4 * c4 + 3], v1.w, a1);
            a2 = __builtin_fmaf(xv[4 * c4 + 0], v2.x, a2);
            a2 = __builtin_fmaf(xv[4 * c4 + 1], v2.y, a2);
            a2 = __builtin_fmaf(xv[4 * c4 + 2], v2.z, a2);
            a2 = __builtin_fmaf(xv[4 * c4 + 3], v2.w, a2);
            a3 = __builtin_fmaf(xv[4 * c4 + 0], v3.x, a3);
            a3 = __builtin_fmaf(xv[4 * c4 + 1], v3.y, a3);
            a3 = __builtin_fmaf(xv[4 * c4 + 2], v3.z, a3);
            a3 = __builtin_fmaf(xv[4 * c4 + 3], v3.w, a3);
        }
        // numpy expression order: (sumsq - M) + cbnorm, elementwise rounding
        float s0 = (a - a0) + cbnorm[e0 + 0];
        float s1 = (a - a1) + cbnorm[e0 + 1];
        float s2 = (a - a2) + cbnorm[e0 + 2];
        float s3 = (a - a3) + cbnorm[e0 + 3];
        // strict < ascending: numpy argmin keeps first occurrence of the min
        if (s0 < best) { best = s0; bidx = e0 + 0; }
        if (s1 < best) { best = s1; bidx = e0 + 1; }
        if (s2 < best) { best = s2; bidx = e0 + 2; }
        if (s3 < best) { best = s3; bidx = e0 + 3; }
    }

    // Write quant_st = x + (quant - x) with numpy's double rounding; accumulate loss.
    const float* qrow = cb + (size_t)bidx * CHANNELS;
    float* op = out + (size_t)b * (CHANNELS * SPATIAL) + s;
    float lsum = 0.0f;
#pragma unroll
    for (int c = 0; c < CHANNELS; ++c) {
        float q = qrow[c];
        float t = q - xv[c];                 // fl(quant - x)
        op[(size_t)c * SPATIAL] = xv[c] + t; // fl(x + t)
        lsum = __builtin_fmaf(t, t, lsum);   // loss has 2% tolerance; order free
    }

    // Block reduction of loss partials -> one atomic per block
    int lane = threadIdx.x & 63;
    int wid  = threadIdx.x >> 6;
#pragma unroll
    for (int off = 32; off > 0; off >>= 1) lsum += __shfl_down(lsum, off, 64);
    __shared__ float wsum[4];
    if (lane == 0) wsum[wid] = lsum;
    __syncthreads();
    if (threadIdx.x == 0) {
        float bs = (wsum[0] + wsum[1]) + (wsum[2] + wsum[3]);
        atomicAdd(loss_slot, bs * LOSS_SCALE);
    }
}

extern "C" void kernel_launch(void* const* d_in, const int* in_sizes, int n_in,
                              void* d_out, int out_size, void* d_ws, size_t ws_size,
                              hipStream_t stream) {
    const float* x  = (const float*)d_in[0];   // 16777216 elems
    const float* cb = (const float*)d_in[1];   // 32768 elems
    float* out = (float*)d_out;                // 16777216 quant_st + 1 loss
    float* cb2    = (float*)d_ws;              // 512*64 floats
    float* cbnorm = cb2 + NUM_EMB * CHANNELS;  // 512 floats
    float* loss_slot = out + OUT_ELEMS;

    vq_prep<<<2, 256, 0, stream>>>(cb, cb2, cbnorm, loss_slot);
    vq_main<<<NPOS / 256, 256, 0, stream>>>(x, cb, cb2, cbnorm, out, loss_slot);
}

// Round 2
// 379.681 us; speedup vs baseline: 1.6452x; 1.6452x over previous
//
#include <hip/hip_runtime.h>
#include <cstdint>
#include <cstddef>

// Problem constants: x (B=8, C=64, H=32, W=32, D=32) fp32; codebook (512, 64) fp32.
#define SPATIAL   32768          // H*W*D
#define CHANNELS  64
#define NUM_EMB   512
#define NPOS      262144         // B * SPATIAL
#define OUT_ELEMS 16777216       // NPOS * CHANNELS
#define HALF_EMB  256            // entries staged in LDS per pass (64 KB)
#define BLOCK     512            // threads per block (8 waves)
// loss = q_loss + 0.25*e_loss = 1.25 * mean((quant-x)^2); 1.25/2^24 exact in fp32
#define LOSS_SCALE (1.25f / 16777216.0f)

// numpy pairwise_sum for n=64 (contiguous): 8 accumulators strided by 8,
// combined ((r0+r1)+(r2+r3))+((r4+r5)+(r6+r7)). Bitwise replication.
__device__ __forceinline__ float np_pairwise_sum64(const float* v) {
#pragma clang fp contract(off)
    float r[8];
#pragma unroll
    for (int j = 0; j < 8; ++j) r[j] = v[j];
#pragma unroll
    for (int i = 8; i < 64; i += 8) {
#pragma unroll
        for (int j = 0; j < 8; ++j) r[j] += v[i + j];
    }
    return ((r[0] + r[1]) + (r[2] + r[3])) + ((r[4] + r[5]) + (r[6] + r[7]));
}

// Prep: cbnorm[e] = numpy-pairwise sum(cb[e]^2); zero the loss slot.
__global__ void vq_prep(const float* __restrict__ cb,
                        float* __restrict__ cbnorm,
                        float* __restrict__ loss_slot) {
#pragma clang fp contract(off)
    int e = blockIdx.x * blockDim.x + threadIdx.x;
    if (e == 0) *loss_slot = 0.0f;
    if (e < NUM_EMB) {
        float sq[CHANNELS];
#pragma unroll
        for (int c = 0; c < CHANNELS; ++c) {
            float v = cb[e * CHANNELS + c];
            sq[c] = v * v;                   // numpy: cb*cb rounded, then summed
        }
        cbnorm[e] = np_pairwise_sum64(sq);
    }
}

__global__ __launch_bounds__(BLOCK, 4) void vq_main(
    const float* __restrict__ x,
    const float* __restrict__ cb,
    const float* __restrict__ cbnorm,
    float* __restrict__ out,
    float* __restrict__ loss_slot) {
#pragma clang fp contract(off)
    // 64 KB LDS: 256 codebook rows of 2*cb, as 16 float4 per row.
    __shared__ float4 cbL[HALF_EMB * 16];

    const int n = blockIdx.x * BLOCK + threadIdx.x;   // position index, < NPOS
    const int b = n >> 15;                            // / SPATIAL
    const int s = n & 32767;                          // % SPATIAL

    const float* xp = x + (size_t)b * (CHANNELS * SPATIAL) + s;

    // Load the 64-channel vector (stride SPATIAL -> coalesced across lanes per c)
    float xv[CHANNELS];
#pragma unroll
    for (int c = 0; c < CHANNELS; ++c) xv[c] = xp[(size_t)c * SPATIAL];

    // ||x||^2, numpy pairwise on elementwise squares
    float sq[CHANNELS];
#pragma unroll
    for (int c = 0; c < CHANNELS; ++c) sq[c] = xv[c] * xv[c];
    const float a = np_pairwise_sum64(sq);

    float best = 3.4e38f;
    int bidx = 0;

    const float4* cb4g = (const float4*)cb;           // 8192 float4 total

    for (int p = 0; p < 2; ++p) {
        // ---- stage 256 entries of 2*cb into LDS (coalesced, exact x2) ----
        const float4* src = cb4g + p * (HALF_EMB * 16);
#pragma unroll
        for (int i = 0; i < (HALF_EMB * 16) / BLOCK; ++i) {
            int idx = threadIdx.x + BLOCK * i;
            float4 v = src[idx];
            float4 w;
            w.x = v.x + v.x; w.y = v.y + v.y; w.z = v.z + v.z; w.w = v.w + v.w;
            cbL[idx] = w;
        }
        __syncthreads();

        const float* cbn = cbnorm + p * HALF_EMB;
        const int ebase = p * HALF_EMB;

        // ---- scan 256 entries: broadcast ds_read_b128 + fma chains ----
        for (int e0 = 0; e0 < HALF_EMB; e0 += 4) {
            float a0 = 0.0f, a1 = 0.0f, a2 = 0.0f, a3 = 0.0f;
            const float4* r = cbL + e0 * 16;
#pragma unroll
            for (int c4 = 0; c4 < 16; ++c4) {
                float4 v0 = r[c4];
                float4 v1 = r[16 + c4];
                float4 v2 = r[32 + c4];
                float4 v3 = r[48 + c4];
                a0 = __builtin_fmaf(xv[4 * c4 + 0], v0.x, a0);
                a0 = __builtin_fmaf(xv[4 * c4 + 1], v0.y, a0);
                a0 = __builtin_fmaf(xv[4 * c4 + 2], v0.z, a0);
                a0 = __builtin_fmaf(xv[4 * c4 + 3], v0.w, a0);
                a1 = __builtin_fmaf(xv[4 * c4 + 0], v1.x, a1);
                a1 = __builtin_fmaf(xv[4 * c4 + 1], v1.y, a1);
                a1 = __builtin_fmaf(xv[4 * c4 + 2], v1.z, a1);
                a1 = __builtin_fmaf(xv[4 * c4 + 3], v1.w, a1);
                a2 = __builtin_fmaf(xv[4 * c4 + 0], v2.x, a2);
                a2 = __builtin_fmaf(xv[4 * c4 + 1], v2.y, a2);
                a2 = __builtin_fmaf(xv[4 * c4 + 2], v2.z, a2);
                a2 = __builtin_fmaf(xv[4 * c4 + 3], v2.w, a2);
                a3 = __builtin_fmaf(xv[4 * c4 + 0], v3.x, a3);
                a3 = __builtin_fmaf(xv[4 * c4 + 1], v3.y, a3);
                a3 = __builtin_fmaf(xv[4 * c4 + 2], v3.z, a3);
                a3 = __builtin_fmaf(xv[4 * c4 + 3], v3.w, a3);
            }
            // numpy expression order: (sumsq - M) + cbnorm, elementwise rounding
            float s0 = (a - a0) + cbn[e0 + 0];
            float s1 = (a - a1) + cbn[e0 + 1];
            float s2 = (a - a2) + cbn[e0 + 2];
            float s3 = (a - a3) + cbn[e0 + 3];
            // strict < ascending: numpy argmin keeps first occurrence of the min
            if (s0 < best) { best = s0; bidx = ebase + e0 + 0; }
            if (s1 < best) { best = s1; bidx = ebase + e0 + 1; }
            if (s2 < best) { best = s2; bidx = ebase + e0 + 2; }
            if (s3 < best) { best = s3; bidx = ebase + e0 + 3; }
        }
        __syncthreads();   // all threads done reading before next-pass staging
    }

    // Write quant_st = x + (quant - x) with numpy's double rounding; accumulate loss.
    const float* qrow = cb + (size_t)bidx * CHANNELS;
    float* op = out + (size_t)b * (CHANNELS * SPATIAL) + s;
    float lsum = 0.0f;
#pragma unroll
    for (int c = 0; c < CHANNELS; ++c) {
        float q = qrow[c];
        float t = q - xv[c];                 // fl(quant - x)
        op[(size_t)c * SPATIAL] = xv[c] + t; // fl(x + t)
        lsum = __builtin_fmaf(t, t, lsum);   // loss has 2% tolerance; order free
    }

    // Block reduction of loss partials -> one atomic per block.
    // Reuse cbL storage for wave sums (all codebook reads are behind the barrier).
    float* wsum = (float*)cbL;
    int lane = threadIdx.x & 63;
    int wid  = threadIdx.x >> 6;   // 8 waves
#pragma unroll
    for (int off = 32; off > 0; off >>= 1) lsum += __shfl_down(lsum, off, 64);
    if (lane == 0) wsum[wid] = lsum;
    __syncthreads();
    if (threadIdx.x == 0) {
        float bs = ((wsum[0] + wsum[1]) + (wsum[2] + wsum[3]))
                 + ((wsum[4] + wsum[5]) + (wsum[6] + wsum[7]));
        atomicAdd(loss_slot, bs * LOSS_SCALE);
    }
}

extern "C" void kernel_launch(void* const* d_in, const int* in_sizes, int n_in,
                              void* d_out, int out_size, void* d_ws, size_t ws_size,
                              hipStream_t stream) {
    const float* x  = (const float*)d_in[0];   // 16777216 elems
    const float* cb = (const float*)d_in[1];   // 32768 elems
    float* out = (float*)d_out;                // 16777216 quant_st + 1 loss
    float* cbnorm = (float*)d_ws;              // 512 floats
    float* loss_slot = out + OUT_ELEMS;

    vq_prep<<<2, 256, 0, stream>>>(cb, cbnorm, loss_slot);
    vq_main<<<NPOS / BLOCK, BLOCK, 0, stream>>>(x, cb, cbnorm, out, loss_slot);
}

// Round 3
// 372.271 us; speedup vs baseline: 1.6779x; 1.0199x over previous
//
#include <hip/hip_runtime.h>
#include <cstdint>
#include <cstddef>

// Problem constants: x (B=8, C=64, H=32, W=32, D=32) fp32; codebook (512, 64) fp32.
#define SPATIAL   32768          // H*W*D
#define CHANNELS  64
#define NUM_EMB   512
#define NPOS      262144         // B * SPATIAL
#define OUT_ELEMS 16777216       // NPOS * CHANNELS
#define HALF_EMB  256            // entries staged in LDS per pass (64 KB)
#define BLOCK     512            // threads per block (8 waves)
// loss = q_loss + 0.25*e_loss = 1.25 * mean((quant-x)^2); 1.25/2^24 exact in fp32
#define LOSS_SCALE (1.25f / 16777216.0f)

// numpy pairwise_sum for n=64 (contiguous): 8 accumulators strided by 8,
// combined ((r0+r1)+(r2+r3))+((r4+r5)+(r6+r7)). Bitwise replication.
__device__ __forceinline__ float np_pairwise_sum64(const float* v) {
#pragma clang fp contract(off)
    float r[8];
#pragma unroll
    for (int j = 0; j < 8; ++j) r[j] = v[j];
#pragma unroll
    for (int i = 8; i < 64; i += 8) {
#pragma unroll
        for (int j = 0; j < 8; ++j) r[j] += v[i + j];
    }
    return ((r[0] + r[1]) + (r[2] + r[3])) + ((r[4] + r[5]) + (r[6] + r[7]));
}

// Prep: cbnorm[e] = numpy-pairwise sum(cb[e]^2); zero the loss slot.
__global__ void vq_prep(const float* __restrict__ cb,
                        float* __restrict__ cbnorm,
                        float* __restrict__ loss_slot) {
#pragma clang fp contract(off)
    int e = blockIdx.x * blockDim.x + threadIdx.x;
    if (e == 0) *loss_slot = 0.0f;
    if (e < NUM_EMB) {
        float sq[CHANNELS];
#pragma unroll
        for (int c = 0; c < CHANNELS; ++c) {
            float v = cb[e * CHANNELS + c];
            sq[c] = v * v;                   // numpy: cb*cb rounded, then summed
        }
        cbnorm[e] = np_pairwise_sum64(sq);
    }
}

// waves_per_eu(4,4): LDS (64 KB/block) caps residency at 2 blocks/CU = 4
// waves/EU regardless; pinning max=4 gives the allocator a 128-VGPR budget
// so xv[64] stays in arch VGPRs. (R2: min=4 alone made the backend chase
// 8 waves/EU -> VGPR_Count=64 -> xv spilled to AGPRs -> ~1 extra
// v_accvgpr_read per FMA -> 2.4x VALU issue. LDS cap makes that pointless.)
__global__ __launch_bounds__(BLOCK)
__attribute__((amdgpu_waves_per_eu(4, 4)))
void vq_main(
    const float* __restrict__ x,
    const float* __restrict__ cb,
    const float* __restrict__ cbnorm,
    float* __restrict__ out,
    float* __restrict__ loss_slot) {
#pragma clang fp contract(off)
    // 64 KB LDS: 256 codebook rows of 2*cb, as 16 float4 per row.
    __shared__ float4 cbL[HALF_EMB * 16];

    const int n = blockIdx.x * BLOCK + threadIdx.x;   // position index, < NPOS
    const int b = n >> 15;                            // / SPATIAL
    const int s = n & 32767;                          // % SPATIAL

    const float* xp = x + (size_t)b * (CHANNELS * SPATIAL) + s;

    // Load the 64-channel vector (stride SPATIAL -> coalesced across lanes per c)
    float xv[CHANNELS];
#pragma unroll
    for (int c = 0; c < CHANNELS; ++c) xv[c] = xp[(size_t)c * SPATIAL];

    // ||x||^2, numpy pairwise on elementwise squares
    float sq[CHANNELS];
#pragma unroll
    for (int c = 0; c < CHANNELS; ++c) sq[c] = xv[c] * xv[c];
    const float a = np_pairwise_sum64(sq);

    float best = 3.4e38f;
    int bidx = 0;

    const float4* cb4g = (const float4*)cb;           // 8192 float4 total

    for (int p = 0; p < 2; ++p) {
        // ---- stage 256 entries of 2*cb into LDS (coalesced, exact x2) ----
        const float4* src = cb4g + p * (HALF_EMB * 16);
#pragma unroll
        for (int i = 0; i < (HALF_EMB * 16) / BLOCK; ++i) {
            int idx = threadIdx.x + BLOCK * i;
            float4 v = src[idx];
            float4 w;
            w.x = v.x + v.x; w.y = v.y + v.y; w.z = v.z + v.z; w.w = v.w + v.w;
            cbL[idx] = w;
        }
        __syncthreads();

        const float* cbn = cbnorm + p * HALF_EMB;
        const int ebase = p * HALF_EMB;

        // ---- scan 256 entries: broadcast ds_read_b128 + fma chains ----
        for (int e0 = 0; e0 < HALF_EMB; e0 += 4) {
            float a0 = 0.0f, a1 = 0.0f, a2 = 0.0f, a3 = 0.0f;
            const float4* r = cbL + e0 * 16;
#pragma unroll
            for (int c4 = 0; c4 < 16; ++c4) {
                float4 v0 = r[c4];
                float4 v1 = r[16 + c4];
                float4 v2 = r[32 + c4];
                float4 v3 = r[48 + c4];
                a0 = __builtin_fmaf(xv[4 * c4 + 0], v0.x, a0);
                a0 = __builtin_fmaf(xv[4 * c4 + 1], v0.y, a0);
                a0 = __builtin_fmaf(xv[4 * c4 + 2], v0.z, a0);
                a0 = __builtin_fmaf(xv[4 * c4 + 3], v0.w, a0);
                a1 = __builtin_fmaf(xv[4 * c4 + 0], v1.x, a1);
                a1 = __builtin_fmaf(xv[4 * c4 + 1], v1.y, a1);
                a1 = __builtin_fmaf(xv[4 * c4 + 2], v1.z, a1);
                a1 = __builtin_fmaf(xv[4 * c4 + 3], v1.w, a1);
                a2 = __builtin_fmaf(xv[4 * c4 + 0], v2.x, a2);
                a2 = __builtin_fmaf(xv[4 * c4 + 1], v2.y, a2);
                a2 = __builtin_fmaf(xv[4 * c4 + 2], v2.z, a2);
                a2 = __builtin_fmaf(xv[4 * c4 + 3], v2.w, a2);
                a3 = __builtin_fmaf(xv[4 * c4 + 0], v3.x, a3);
                a3 = __builtin_fmaf(xv[4 * c4 + 1], v3.y, a3);
                a3 = __builtin_fmaf(xv[4 * c4 + 2], v3.z, a3);
                a3 = __builtin_fmaf(xv[4 * c4 + 3], v3.w, a3);
            }
            // numpy expression order: (sumsq - M) + cbnorm, elementwise rounding
            float s0 = (a - a0) + cbn[e0 + 0];
            float s1 = (a - a1) + cbn[e0 + 1];
            float s2 = (a - a2) + cbn[e0 + 2];
            float s3 = (a - a3) + cbn[e0 + 3];
            // strict < ascending: numpy argmin keeps first occurrence of the min
            if (s0 < best) { best = s0; bidx = ebase + e0 + 0; }
            if (s1 < best) { best = s1; bidx = ebase + e0 + 1; }
            if (s2 < best) { best = s2; bidx = ebase + e0 + 2; }
            if (s3 < best) { best = s3; bidx = ebase + e0 + 3; }
        }
        __syncthreads();   // all threads done reading before next-pass staging
    }

    // Write quant_st = x + (quant - x) with numpy's double rounding; accumulate loss.
    const float* qrow = cb + (size_t)bidx * CHANNELS;
    float* op = out + (size_t)b * (CHANNELS * SPATIAL) + s;
    float lsum = 0.0f;
#pragma unroll
    for (int c = 0; c < CHANNELS; ++c) {
        float q = qrow[c];
        float t = q - xv[c];                 // fl(quant - x)
        op[(size_t)c * SPATIAL] = xv[c] + t; // fl(x + t)
        lsum = __builtin_fmaf(t, t, lsum);   // loss has 2% tolerance; order free
    }

    // Block reduction of loss partials -> one atomic per block.
    // Reuse cbL storage for wave sums (all codebook reads are behind the barrier).
    float* wsum = (float*)cbL;
    int lane = threadIdx.x & 63;
    int wid  = threadIdx.x >> 6;   // 8 waves
#pragma unroll
    for (int off = 32; off > 0; off >>= 1) lsum += __shfl_down(lsum, off, 64);
    if (lane == 0) wsum[wid] = lsum;
    __syncthreads();
    if (threadIdx.x == 0) {
        float bs = ((wsum[0] + wsum[1]) + (wsum[2] + wsum[3]))
                 + ((wsum[4] + wsum[5]) + (wsum[6] + wsum[7]));
        atomicAdd(loss_slot, bs * LOSS_SCALE);
    }
}

extern "C" void kernel_launch(void* const* d_in, const int* in_sizes, int n_in,
                              void* d_out, int out_size, void* d_ws, size_t ws_size,
                              hipStream_t stream) {
    const float* x  = (const float*)d_in[0];   // 16777216 elems
    const float* cb = (const float*)d_in[1];   // 32768 elems
    float* out = (float*)d_out;                // 16777216 quant_st + 1 loss
    float* cbnorm = (float*)d_ws;              // 512 floats
    float* loss_slot = out + OUT_ELEMS;

    vq_prep<<<2, 256, 0, stream>>>(cb, cbnorm, loss_slot);
    vq_main<<<NPOS / BLOCK, BLOCK, 0, stream>>>(x, cb, cbnorm, out, loss_slot);
}